// Round 9
// baseline (199.225 us; speedup 1.0000x reference)
//
#include <hip/hip_runtime.h>

#define B_TOK 4096
#define DDIM  1024
#define HDIM  2048
#define NEXP  8
#define MAXTOK 4096
#define BM 128
#define BN 128
#define BK 64

// ws byte offsets (total ~120.3 MB)
#define OFF_W1T  0ull                      // bf16 [E][H][D]  33554432
#define OFF_W2T  33554432ull               // bf16 [E][D][H]  33554432
#define OFF_XB   67108864ull               // bf16 [B][D]      8388608
#define OFF_H    75497472ull               // bf16 [8192][H]  33554432
#define OFF_Y    109051904ull              // bf16 [8192][D]  16777216
#define OFF_TOK  125829120ull              // int  [E][4096]    131072
#define OFF_GATE 125960192ull              // f32  [E][4096]    131072
#define OFF_PAIR 126091264ull              // int  [B][2]        32768
#define OFF_CNT  126124032ull              // int[16]
#define OFF_OFFS 126124096ull              // int[16]
// eidx/gco overlap the ybuf region (dead until fc2; consumed by build_kernel)
#define OFF_EIDX (OFF_Y)                   // int  [B]           16384
#define OFF_GCO  (OFF_Y + 16384ull)        // f32  [B]           16384

typedef __attribute__((ext_vector_type(4))) float f32x4;
typedef __attribute__((ext_vector_type(8))) short bf16x8;

static __device__ __forceinline__ unsigned short f2bf(float f) {
    unsigned u = __builtin_bit_cast(unsigned, f);
    unsigned r = (u + 0x7FFFu + ((u >> 16) & 1u)) >> 16;
    return (unsigned short)r;
}
static __device__ __forceinline__ float bf2f(unsigned short s) {
    unsigned u = ((unsigned)s) << 16;
    return __builtin_bit_cast(float, u);
}

#define AS1(p) ((const __attribute__((address_space(1))) void*)(p))
#define AS3(p) ((__attribute__((address_space(3))) void*)(p))

// ---------------- gating phase A: logits + top-2 + softmax + x->bf16 ----------------
__global__ void __launch_bounds__(256) gating_logits_kernel(
    const float* __restrict__ x, const float* __restrict__ wg,
    int* __restrict__ eidx, float* __restrict__ gco, short* __restrict__ Xb) {
    int wave = threadIdx.x >> 6;
    int lane = threadIdx.x & 63;
    int b = blockIdx.x * 4 + wave;
    float acc[NEXP];
#pragma unroll
    for (int e = 0; e < NEXP; e++) acc[e] = 0.f;
    const float* xr = x + (size_t)b * DDIM;
    short* xbr = Xb + (size_t)b * DDIM;
#pragma unroll
    for (int i = 0; i < DDIM / 64; i++) {
        int d = i * 64 + lane;
        float xv = xr[d];
        xbr[d] = (short)f2bf(xv);
        const float4* wrow = (const float4*)(wg + (size_t)d * NEXP);
        float4 w0 = wrow[0], w1 = wrow[1];
        acc[0] += xv * w0.x; acc[1] += xv * w0.y; acc[2] += xv * w0.z; acc[3] += xv * w0.w;
        acc[4] += xv * w1.x; acc[5] += xv * w1.y; acc[6] += xv * w1.z; acc[7] += xv * w1.w;
    }
#pragma unroll
    for (int off = 32; off >= 1; off >>= 1)
#pragma unroll
        for (int e = 0; e < NEXP; e++) acc[e] += __shfl_xor(acc[e], off);
    if (lane == 0) {
        int i1 = 0; float m1 = acc[0];
        for (int e = 1; e < NEXP; e++) if (acc[e] > m1) { m1 = acc[e]; i1 = e; }
        int i2 = (i1 == 0) ? 1 : 0; float m2 = -1e30f;
        for (int e = 0; e < NEXP; e++) { if (e == i1) continue; if (acc[e] > m2) { m2 = acc[e]; i2 = e; } }
        float g1 = 1.f / (1.f + expf(m2 - m1));
        eidx[b] = i1 | (i2 << 16);
        gco[b] = g1;
    }
}

// ---------------- gating phase B: list build, LDS histogram + 1 global atomic/expert/block ----
__global__ void __launch_bounds__(256) build_kernel(
    const int* __restrict__ eidx, const float* __restrict__ gco,
    int* __restrict__ counts, int* __restrict__ tok,
    float* __restrict__ gate, int* __restrict__ pair) {
    __shared__ int lhist[NEXP];
    __shared__ int gbase[NEXP];
    int t = threadIdx.x;
    if (t < NEXP) lhist[t] = 0;
    __syncthreads();
    int b = blockIdx.x * 256 + t;
    int ep = eidx[b];
    int e1 = ep & 0xffff, e2 = ep >> 16;
    float g1 = gco[b], g2 = 1.f - g1;
    int l1 = atomicAdd(&lhist[e1], 1);
    int l2 = atomicAdd(&lhist[e2], 1);
    __syncthreads();
    if (t < NEXP) gbase[t] = atomicAdd(&counts[t], lhist[t]);
    __syncthreads();
    int s1 = gbase[e1] + l1, s2 = gbase[e2] + l2;
    tok[e1 * MAXTOK + s1] = b; gate[e1 * MAXTOK + s1] = g1; pair[b * 2 + 0] = e1 * MAXTOK + s1;
    tok[e2 * MAXTOK + s2] = b; gate[e2 * MAXTOK + s2] = g2; pair[b * 2 + 1] = e2 * MAXTOK + s2;
}

__global__ void scan_kernel(const int* __restrict__ counts, int* __restrict__ offs) {
    if (threadIdx.x == 0) {
        int s = 0;
        for (int e = 0; e < NEXP; e++) { offs[e] = s; s += counts[e]; }
    }
}

// ---------------- per-expert transpose + f32->bf16: [R][C] -> [C][R] ----------------
__global__ void __launch_bounds__(256) tcvt_kernel(const float* __restrict__ src, short* __restrict__ dst,
                                                   int R, int C) {
    __shared__ float tile[64][65];
    int e = blockIdx.z;
    size_t base = (size_t)e * R * C;
    int r0 = blockIdx.y * 64, c0 = blockIdx.x * 64;
    int t = threadIdx.x;
    int rr = t >> 4, c4 = (t & 15) * 4;
    const float* s = src + base + (size_t)r0 * C + c0;
#pragma unroll
    for (int i = 0; i < 4; i++) {
        float4 v = *(const float4*)(s + (size_t)(rr + i * 16) * C + c4);
        tile[rr + i * 16][c4 + 0] = v.x; tile[rr + i * 16][c4 + 1] = v.y;
        tile[rr + i * 16][c4 + 2] = v.z; tile[rr + i * 16][c4 + 3] = v.w;
    }
    __syncthreads();
    short* d = dst + base + (size_t)c0 * R + r0;
    int hr0 = t >> 4, dc = (t & 15) * 4;
#pragma unroll
    for (int i = 0; i < 4; i++) {
        int hr = hr0 + i * 16;
        short4 o;
        o.x = (short)f2bf(tile[dc + 0][hr]); o.y = (short)f2bf(tile[dc + 1][hr]);
        o.z = (short)f2bf(tile[dc + 2][hr]); o.w = (short)f2bf(tile[dc + 3][hr]);
        *(short4*)(d + (size_t)hr * R + dc) = o;
    }
}

// ============ fc1: h[slot][H] = relu(X[tok] @ W1T^T + b1), bf16 out ============
// Proper 2-phase (T3 minimum recipe): STAGE(next) issued BEFORE ds_read+MFMA(cur),
// ONE __syncthreads per K-step at the end (drain lands after the MFMAs).
// BK=64 zero-conflict swizzle, gload_lds 16B, XCD affinity, 4 waves x 64x64.
__global__ void __launch_bounds__(256, 2) fc1_kernel(
    const short* __restrict__ Xb, const short* __restrict__ W1T, const float* __restrict__ b1,
    short* __restrict__ h, const int* __restrict__ tok,
    const int* __restrict__ counts, const int* __restrict__ offs) {
    int bid = blockIdx.x;
    int e = bid & 7;
    int r2 = bid >> 3;                  // 0..511
    int m0 = (r2 & 31) * BM;
    int n0 = (r2 >> 5) * BN;
    int cnt = counts[e];
    if (m0 >= cnt) return;
    int baseh = offs[e];

    __shared__ short As[2][BM * BK];   // 16 KB each
    __shared__ short Bs[2][BN * BK];

    int t = threadIdx.x;
    int wave = t >> 6, lane = t & 63;

    // staging: 1024 granules of 16B per matrix; thread t, load i -> granule G=i*256+t
    const short* asrc[4]; const short* bsrc[4];
    int dsto[4];
#pragma unroll
    for (int i = 0; i < 4; i++) {
        int G = i * 256 + t;
        int r = G >> 3, q = G & 7;
        int cks = ((q ^ (r & 7)) << 3);            // pre-swizzled source chunk (shorts)
        int trow = m0 + r;
        int tid2 = (trow < cnt) ? tok[e * MAXTOK + trow] : 0;
        asrc[i] = Xb + (size_t)tid2 * DDIM + cks;
        bsrc[i] = W1T + ((size_t)e * HDIM + n0 + r) * DDIM + cks;
        dsto[i] = G * 8;                           // linear LDS dest (shorts)
    }

    int wr = (wave >> 1) * 64, wc = (wave & 1) * 64;
    f32x4 acc[4][4];
    f32x4 zero = {0.f, 0.f, 0.f, 0.f};
#pragma unroll
    for (int m = 0; m < 4; m++)
#pragma unroll
        for (int n = 0; n < 4; n++) acc[m][n] = zero;

    int l15 = lane & 15, l7 = lane & 7, lhi = lane >> 4;
    int aoff[4][2], boff[4][2];
#pragma unroll
    for (int ks = 0; ks < 2; ks++) {
        int q = (lhi + ks * 4) ^ l7;
#pragma unroll
        for (int m = 0; m < 4; m++) {
            aoff[m][ks] = (wr + m * 16 + l15) * BK + (q << 3);
            boff[m][ks] = (wc + m * 16 + l15) * BK + (q << 3);
        }
    }

#define STAGE1(buf, k0) do { \
    _Pragma("unroll") \
    for (int i = 0; i < 4; i++) { \
        __builtin_amdgcn_global_load_lds(AS1(asrc[i] + (k0)), AS3(&As[buf][dsto[i]]), 16, 0, 0); \
        __builtin_amdgcn_global_load_lds(AS1(bsrc[i] + (k0)), AS3(&Bs[buf][dsto[i]]), 16, 0, 0); \
    } \
} while (0)

    STAGE1(0, 0);
    __syncthreads();
    int cur = 0;
    const int NT = DDIM / BK;
    for (int kt = 0; kt < NT; ++kt) {
        if (kt < NT - 1) STAGE1(cur ^ 1, (kt + 1) * BK);
#pragma unroll
        for (int ks = 0; ks < 2; ks++) {
            bf16x8 af[4], bg[4];
#pragma unroll
            for (int m = 0; m < 4; m++) {
                af[m] = *(const bf16x8*)(&As[cur][aoff[m][ks]]);
                bg[m] = *(const bf16x8*)(&Bs[cur][boff[m][ks]]);
            }
            __builtin_amdgcn_s_setprio(1);
#pragma unroll
            for (int m = 0; m < 4; m++)
#pragma unroll
                for (int n = 0; n < 4; n++)
                    acc[m][n] = __builtin_amdgcn_mfma_f32_16x16x32_bf16(bg[n], af[m], acc[m][n], 0, 0, 0);
            __builtin_amdgcn_s_setprio(0);
        }
        __syncthreads();    // drain (vmcnt 0) lands AFTER the MFMAs; one barrier/K-step
        cur ^= 1;
    }
#undef STAGE1

    // epilogue: D 4-reg axis = output columns -> short4 stores
#pragma unroll
    for (int m = 0; m < 4; m++) {
        int row = m0 + wr + m * 16 + l15;
        if (row < cnt) {
            size_t rb = (size_t)(baseh + row) * HDIM;
#pragma unroll
            for (int n = 0; n < 4; n++) {
                int colb = n0 + wc + n * 16 + (lhi << 2);
                float4 bias = *(const float4*)(b1 + e * HDIM + colb);
                float v0 = acc[m][n][0] + bias.x; v0 = v0 > 0.f ? v0 : 0.f;
                float v1 = acc[m][n][1] + bias.y; v1 = v1 > 0.f ? v1 : 0.f;
                float v2 = acc[m][n][2] + bias.z; v2 = v2 > 0.f ? v2 : 0.f;
                float v3 = acc[m][n][3] + bias.w; v3 = v3 > 0.f ? v3 : 0.f;
                short4 o;
                o.x = (short)f2bf(v0); o.y = (short)f2bf(v1);
                o.z = (short)f2bf(v2); o.w = (short)f2bf(v3);
                *(short4*)(h + rb + colb) = o;
            }
        }
    }
}

// ============ fc2: y[slot][D] = h[slot] @ W2T^T + b2, bf16 out ============
__global__ void __launch_bounds__(256, 2) fc2_kernel(
    const short* __restrict__ h, const short* __restrict__ W2T, const float* __restrict__ b2,
    short* __restrict__ ybuf, const int* __restrict__ counts, const int* __restrict__ offs) {
    int bid = blockIdx.x;
    int e = bid & 7;
    int r2 = bid >> 3;                  // 0..255
    int m0 = (r2 & 31) * BM;
    int n0 = (r2 >> 5) * BN;
    int cnt = counts[e];
    if (m0 >= cnt) return;
    int baseh = offs[e];

    __shared__ short As[2][BM * BK];
    __shared__ short Bs[2][BN * BK];

    int t = threadIdx.x;
    int wave = t >> 6, lane = t & 63;

    const short* asrc[4]; const short* bsrc[4];
    int dsto[4];
#pragma unroll
    for (int i = 0; i < 4; i++) {
        int G = i * 256 + t;
        int r = G >> 3, q = G & 7;
        int cks = ((q ^ (r & 7)) << 3);
        asrc[i] = h + (size_t)(baseh + m0 + r) * HDIM + cks;   // overreads stay inside ws
        bsrc[i] = W2T + ((size_t)e * DDIM + n0 + r) * HDIM + cks;
        dsto[i] = G * 8;
    }

    int wr = (wave >> 1) * 64, wc = (wave & 1) * 64;
    f32x4 acc[4][4];
    f32x4 zero = {0.f, 0.f, 0.f, 0.f};
#pragma unroll
    for (int m = 0; m < 4; m++)
#pragma unroll
        for (int n = 0; n < 4; n++) acc[m][n] = zero;

    int l15 = lane & 15, l7 = lane & 7, lhi = lane >> 4;
    int aoff[4][2], boff[4][2];
#pragma unroll
    for (int ks = 0; ks < 2; ks++) {
        int q = (lhi + ks * 4) ^ l7;
#pragma unroll
        for (int m = 0; m < 4; m++) {
            aoff[m][ks] = (wr + m * 16 + l15) * BK + (q << 3);
            boff[m][ks] = (wc + m * 16 + l15) * BK + (q << 3);
        }
    }

#define STAGE2(buf, k0) do { \
    _Pragma("unroll") \
    for (int i = 0; i < 4; i++) { \
        __builtin_amdgcn_global_load_lds(AS1(asrc[i] + (k0)), AS3(&As[buf][dsto[i]]), 16, 0, 0); \
        __builtin_amdgcn_global_load_lds(AS1(bsrc[i] + (k0)), AS3(&Bs[buf][dsto[i]]), 16, 0, 0); \
    } \
} while (0)

    STAGE2(0, 0);
    __syncthreads();
    int cur = 0;
    const int NT = HDIM / BK;
    for (int kt = 0; kt < NT; ++kt) {
        if (kt < NT - 1) STAGE2(cur ^ 1, (kt + 1) * BK);
#pragma unroll
        for (int ks = 0; ks < 2; ks++) {
            bf16x8 af[4], bg[4];
#pragma unroll
            for (int m = 0; m < 4; m++) {
                af[m] = *(const bf16x8*)(&As[cur][aoff[m][ks]]);
                bg[m] = *(const bf16x8*)(&Bs[cur][boff[m][ks]]);
            }
            __builtin_amdgcn_s_setprio(1);
#pragma unroll
            for (int m = 0; m < 4; m++)
#pragma unroll
                for (int n = 0; n < 4; n++)
                    acc[m][n] = __builtin_amdgcn_mfma_f32_16x16x32_bf16(bg[n], af[m], acc[m][n], 0, 0, 0);
            __builtin_amdgcn_s_setprio(0);
        }
        __syncthreads();
        cur ^= 1;
    }
#undef STAGE2

#pragma unroll
    for (int m = 0; m < 4; m++) {
        int row = m0 + wr + m * 16 + l15;
        if (row < cnt) {
            size_t rb = (size_t)(baseh + row) * DDIM;
#pragma unroll
            for (int n = 0; n < 4; n++) {
                int colb = n0 + wc + n * 16 + (lhi << 2);
                float4 bias = *(const float4*)(b2 + e * DDIM + colb);
                short4 o;
                o.x = (short)f2bf(acc[m][n][0] + bias.x);
                o.y = (short)f2bf(acc[m][n][1] + bias.y);
                o.z = (short)f2bf(acc[m][n][2] + bias.z);
                o.w = (short)f2bf(acc[m][n][3] + bias.w);
                *(short4*)(ybuf + rb + colb) = o;
            }
        }
    }
}

// ---------------- combine: out[b] = g0*y[slot0] + g1*y[slot1] ----------------
__global__ void __launch_bounds__(256) combine_kernel(
    const short* __restrict__ ybuf, const float* __restrict__ gate,
    const int* __restrict__ pair, const int* __restrict__ offs, float* __restrict__ out) {
    int b = blockIdx.x;
    int p0 = pair[b * 2], p1 = pair[b * 2 + 1];
    float g0 = gate[p0], g1 = gate[p1];
    int r0 = offs[p0 >> 12] + (p0 & 4095);
    int r1 = offs[p1 >> 12] + (p1 & 4095);
    const short4* y0 = (const short4*)(ybuf + (size_t)r0 * DDIM);
    const short4* y1 = (const short4*)(ybuf + (size_t)r1 * DDIM);
    float4* o = (float4*)(out + (size_t)b * DDIM);
    int t = threadIdx.x;           // 256 threads * 4 elems = 1024 = DDIM
    short4 a = y0[t], c = y1[t];
    float4 v;
    v.x = g0 * bf2f((unsigned short)a.x) + g1 * bf2f((unsigned short)c.x);
    v.y = g0 * bf2f((unsigned short)a.y) + g1 * bf2f((unsigned short)c.y);
    v.z = g0 * bf2f((unsigned short)a.z) + g1 * bf2f((unsigned short)c.z);
    v.w = g0 * bf2f((unsigned short)a.w) + g1 * bf2f((unsigned short)c.w);
    o[t] = v;
}

extern "C" void kernel_launch(void* const* d_in, const int* in_sizes, int n_in,
                              void* d_out, int out_size, void* d_ws, size_t ws_size,
                              hipStream_t stream) {
    const float* x  = (const float*)d_in[0];
    const float* wg = (const float*)d_in[1];
    const float* W1 = (const float*)d_in[2];
    const float* b1 = (const float*)d_in[3];
    const float* W2 = (const float*)d_in[4];
    const float* b2 = (const float*)d_in[5];
    float* out = (float*)d_out;
    char* ws = (char*)d_ws;

    short* W1T = (short*)(ws + OFF_W1T);
    short* W2T = (short*)(ws + OFF_W2T);
    short* Xb  = (short*)(ws + OFF_XB);
    short* h   = (short*)(ws + OFF_H);
    short* ybuf = (short*)(ws + OFF_Y);
    int* tok   = (int*)(ws + OFF_TOK);
    float* gate = (float*)(ws + OFF_GATE);
    int* pair  = (int*)(ws + OFF_PAIR);
    int* counts = (int*)(ws + OFF_CNT);
    int* offs  = (int*)(ws + OFF_OFFS);
    int* eidx  = (int*)(ws + OFF_EIDX);
    float* gco = (float*)(ws + OFF_GCO);

    hipMemsetAsync(counts, 0, 64, stream);
    gating_logits_kernel<<<B_TOK / 4, 256, 0, stream>>>(x, wg, eidx, gco, Xb);
    build_kernel<<<B_TOK / 256, 256, 0, stream>>>(eidx, gco, counts, tok, gate, pair);
    scan_kernel<<<1, 64, 0, stream>>>(counts, offs);
    tcvt_kernel<<<dim3(HDIM / 64, DDIM / 64, NEXP), 256, 0, stream>>>(W1, W1T, DDIM, HDIM);
    tcvt_kernel<<<dim3(DDIM / 64, HDIM / 64, NEXP), 256, 0, stream>>>(W2, W2T, HDIM, DDIM);
    fc1_kernel<<<NEXP * 32 * (HDIM / BN), 256, 0, stream>>>(Xb, W1T, b1, h, tok, counts, offs);
    fc2_kernel<<<NEXP * 32 * (DDIM / BN), 256, 0, stream>>>(h, W2T, b2, ybuf, counts, offs);
    combine_kernel<<<B_TOK, 256, 0, stream>>>(ybuf, gate, pair, offs, out);
}

// Round 10
// 180.801 us; speedup vs baseline: 1.1019x; 1.1019x over previous
//
#include <hip/hip_runtime.h>

#define B_TOK 4096
#define DDIM  1024
#define HDIM  2048
#define NEXP  8
#define MAXTOK 4096
#define BM 128
#define BN 128
#define BK 64
// fc2 tile
#define BM2 64
#define BN2 128

// ws byte offsets (total ~120.3 MB)
#define OFF_W1T  0ull                      // bf16 [E][H][D]  33554432
#define OFF_W2T  33554432ull               // bf16 [E][D][H]  33554432
#define OFF_XB   67108864ull               // bf16 [B][D]      8388608
#define OFF_H    75497472ull               // bf16 [8192][H]  33554432
#define OFF_Y    109051904ull              // bf16 [8192][D]  16777216
#define OFF_TOK  125829120ull              // int  [E][4096]    131072
#define OFF_GATE 125960192ull              // f32  [E][4096]    131072
#define OFF_PAIR 126091264ull              // int  [B][2]        32768
#define OFF_CNT  126124032ull              // int[16]
#define OFF_OFFS 126124096ull              // int[16]
// eidx/gco overlap the ybuf region (dead until fc2; consumed by build_kernel)
#define OFF_EIDX (OFF_Y)                   // int  [B]           16384
#define OFF_GCO  (OFF_Y + 16384ull)        // f32  [B]           16384

typedef __attribute__((ext_vector_type(4))) float f32x4;
typedef __attribute__((ext_vector_type(8))) short bf16x8;

static __device__ __forceinline__ unsigned short f2bf(float f) {
    unsigned u = __builtin_bit_cast(unsigned, f);
    unsigned r = (u + 0x7FFFu + ((u >> 16) & 1u)) >> 16;
    return (unsigned short)r;
}
static __device__ __forceinline__ float bf2f(unsigned short s) {
    unsigned u = ((unsigned)s) << 16;
    return __builtin_bit_cast(float, u);
}

#define AS1(p) ((const __attribute__((address_space(1))) void*)(p))
#define AS3(p) ((__attribute__((address_space(3))) void*)(p))

// ---------------- gating phase A: logits + top-2 + softmax + x->bf16 ----------------
__global__ void __launch_bounds__(256) gating_logits_kernel(
    const float* __restrict__ x, const float* __restrict__ wg,
    int* __restrict__ eidx, float* __restrict__ gco, short* __restrict__ Xb) {
    int wave = threadIdx.x >> 6;
    int lane = threadIdx.x & 63;
    int b = blockIdx.x * 4 + wave;
    float acc[NEXP];
#pragma unroll
    for (int e = 0; e < NEXP; e++) acc[e] = 0.f;
    const float* xr = x + (size_t)b * DDIM;
    short* xbr = Xb + (size_t)b * DDIM;
#pragma unroll
    for (int i = 0; i < DDIM / 64; i++) {
        int d = i * 64 + lane;
        float xv = xr[d];
        xbr[d] = (short)f2bf(xv);
        const float4* wrow = (const float4*)(wg + (size_t)d * NEXP);
        float4 w0 = wrow[0], w1 = wrow[1];
        acc[0] += xv * w0.x; acc[1] += xv * w0.y; acc[2] += xv * w0.z; acc[3] += xv * w0.w;
        acc[4] += xv * w1.x; acc[5] += xv * w1.y; acc[6] += xv * w1.z; acc[7] += xv * w1.w;
    }
#pragma unroll
    for (int off = 32; off >= 1; off >>= 1)
#pragma unroll
        for (int e = 0; e < NEXP; e++) acc[e] += __shfl_xor(acc[e], off);
    if (lane == 0) {
        int i1 = 0; float m1 = acc[0];
        for (int e = 1; e < NEXP; e++) if (acc[e] > m1) { m1 = acc[e]; i1 = e; }
        int i2 = (i1 == 0) ? 1 : 0; float m2 = -1e30f;
        for (int e = 0; e < NEXP; e++) { if (e == i1) continue; if (acc[e] > m2) { m2 = acc[e]; i2 = e; } }
        float g1 = 1.f / (1.f + expf(m2 - m1));
        eidx[b] = i1 | (i2 << 16);
        gco[b] = g1;
    }
}

// ---------------- gating phase B: list build, LDS histogram + 1 global atomic/expert/block ----
__global__ void __launch_bounds__(256) build_kernel(
    const int* __restrict__ eidx, const float* __restrict__ gco,
    int* __restrict__ counts, int* __restrict__ tok,
    float* __restrict__ gate, int* __restrict__ pair) {
    __shared__ int lhist[NEXP];
    __shared__ int gbase[NEXP];
    int t = threadIdx.x;
    if (t < NEXP) lhist[t] = 0;
    __syncthreads();
    int b = blockIdx.x * 256 + t;
    int ep = eidx[b];
    int e1 = ep & 0xffff, e2 = ep >> 16;
    float g1 = gco[b], g2 = 1.f - g1;
    int l1 = atomicAdd(&lhist[e1], 1);
    int l2 = atomicAdd(&lhist[e2], 1);
    __syncthreads();
    if (t < NEXP) gbase[t] = atomicAdd(&counts[t], lhist[t]);
    __syncthreads();
    int s1 = gbase[e1] + l1, s2 = gbase[e2] + l2;
    tok[e1 * MAXTOK + s1] = b; gate[e1 * MAXTOK + s1] = g1; pair[b * 2 + 0] = e1 * MAXTOK + s1;
    tok[e2 * MAXTOK + s2] = b; gate[e2 * MAXTOK + s2] = g2; pair[b * 2 + 1] = e2 * MAXTOK + s2;
}

__global__ void scan_kernel(const int* __restrict__ counts, int* __restrict__ offs) {
    if (threadIdx.x == 0) {
        int s = 0;
        for (int e = 0; e < NEXP; e++) { offs[e] = s; s += counts[e]; }
    }
}

// ---------------- per-expert transpose + f32->bf16: [R][C] -> [C][R] ----------------
__global__ void __launch_bounds__(256) tcvt_kernel(const float* __restrict__ src, short* __restrict__ dst,
                                                   int R, int C) {
    __shared__ float tile[64][65];
    int e = blockIdx.z;
    size_t base = (size_t)e * R * C;
    int r0 = blockIdx.y * 64, c0 = blockIdx.x * 64;
    int t = threadIdx.x;
    int rr = t >> 4, c4 = (t & 15) * 4;
    const float* s = src + base + (size_t)r0 * C + c0;
#pragma unroll
    for (int i = 0; i < 4; i++) {
        float4 v = *(const float4*)(s + (size_t)(rr + i * 16) * C + c4);
        tile[rr + i * 16][c4 + 0] = v.x; tile[rr + i * 16][c4 + 1] = v.y;
        tile[rr + i * 16][c4 + 2] = v.z; tile[rr + i * 16][c4 + 3] = v.w;
    }
    __syncthreads();
    short* d = dst + base + (size_t)c0 * R + r0;
    int hr0 = t >> 4, dc = (t & 15) * 4;
#pragma unroll
    for (int i = 0; i < 4; i++) {
        int hr = hr0 + i * 16;
        short4 o;
        o.x = (short)f2bf(tile[dc + 0][hr]); o.y = (short)f2bf(tile[dc + 1][hr]);
        o.z = (short)f2bf(tile[dc + 2][hr]); o.w = (short)f2bf(tile[dc + 3][hr]);
        *(short4*)(d + (size_t)hr * R + dc) = o;
    }
}

// ============ fc1: h[slot][H] = relu(X[tok] @ W1T^T + b1), bf16 out ============
// R8 proven structure: 1-phase, single 32KB LDS buffer, BK=64 zero-conflict
// swizzle, 4 waves x 64x64, ~4 blocks/CU cross-block TLP, XCD affinity.
__global__ void __launch_bounds__(256, 3) fc1_kernel(
    const short* __restrict__ Xb, const short* __restrict__ W1T, const float* __restrict__ b1,
    short* __restrict__ h, const int* __restrict__ tok,
    const int* __restrict__ counts, const int* __restrict__ offs) {
    int bid = blockIdx.x;
    int e = bid & 7;
    int r2 = bid >> 3;                  // 0..511
    int m0 = (r2 & 31) * BM;
    int n0 = (r2 >> 5) * BN;
    int cnt = counts[e];
    if (m0 >= cnt) return;
    int baseh = offs[e];

    __shared__ short As[BM * BK];   // 16 KB
    __shared__ short Bs[BN * BK];   // 16 KB

    int t = threadIdx.x;
    int wave = t >> 6, lane = t & 63;

    const short* asrc[4]; const short* bsrc[4];
    int dsto[4];
#pragma unroll
    for (int i = 0; i < 4; i++) {
        int G = i * 256 + t;
        int r = G >> 3, q = G & 7;
        int cks = ((q ^ (r & 7)) << 3);            // pre-swizzled source chunk (shorts)
        int trow = m0 + r;
        int tid2 = (trow < cnt) ? tok[e * MAXTOK + trow] : 0;
        asrc[i] = Xb + (size_t)tid2 * DDIM + cks;
        bsrc[i] = W1T + ((size_t)e * HDIM + n0 + r) * DDIM + cks;
        dsto[i] = G * 8;                           // linear LDS dest (shorts)
    }

    int wr = (wave >> 1) * 64, wc = (wave & 1) * 64;
    f32x4 acc[4][4];
    f32x4 zero = {0.f, 0.f, 0.f, 0.f};
#pragma unroll
    for (int m = 0; m < 4; m++)
#pragma unroll
        for (int n = 0; n < 4; n++) acc[m][n] = zero;

    int l15 = lane & 15, l7 = lane & 7, lhi = lane >> 4;
    int aoff[4][2], boff[4][2];
#pragma unroll
    for (int ks = 0; ks < 2; ks++) {
        int q = (lhi + ks * 4) ^ l7;
#pragma unroll
        for (int m = 0; m < 4; m++) {
            aoff[m][ks] = (wr + m * 16 + l15) * BK + (q << 3);
            boff[m][ks] = (wc + m * 16 + l15) * BK + (q << 3);
        }
    }

    const int NT = DDIM / BK;
    for (int kt = 0; kt < NT; ++kt) {
        int k0 = kt * BK;
#pragma unroll
        for (int i = 0; i < 4; i++) {
            __builtin_amdgcn_global_load_lds(AS1(asrc[i] + k0), AS3(&As[dsto[i]]), 16, 0, 0);
            __builtin_amdgcn_global_load_lds(AS1(bsrc[i] + k0), AS3(&Bs[dsto[i]]), 16, 0, 0);
        }
        __syncthreads();
#pragma unroll
        for (int ks = 0; ks < 2; ks++) {
            bf16x8 af[4], bg[4];
#pragma unroll
            for (int m = 0; m < 4; m++) {
                af[m] = *(const bf16x8*)(&As[aoff[m][ks]]);
                bg[m] = *(const bf16x8*)(&Bs[boff[m][ks]]);
            }
            __builtin_amdgcn_s_setprio(1);
#pragma unroll
            for (int m = 0; m < 4; m++)
#pragma unroll
                for (int n = 0; n < 4; n++)
                    acc[m][n] = __builtin_amdgcn_mfma_f32_16x16x32_bf16(bg[n], af[m], acc[m][n], 0, 0, 0);
            __builtin_amdgcn_s_setprio(0);
        }
        __syncthreads();
    }

    // epilogue: D 4-reg axis = output columns -> short4 stores
#pragma unroll
    for (int m = 0; m < 4; m++) {
        int row = m0 + wr + m * 16 + l15;
        if (row < cnt) {
            size_t rb = (size_t)(baseh + row) * HDIM;
#pragma unroll
            for (int n = 0; n < 4; n++) {
                int colb = n0 + wc + n * 16 + (lhi << 2);
                float4 bias = *(const float4*)(b1 + e * HDIM + colb);
                float v0 = acc[m][n][0] + bias.x; v0 = v0 > 0.f ? v0 : 0.f;
                float v1 = acc[m][n][1] + bias.y; v1 = v1 > 0.f ? v1 : 0.f;
                float v2 = acc[m][n][2] + bias.z; v2 = v2 > 0.f ? v2 : 0.f;
                float v3 = acc[m][n][3] + bias.w; v3 = v3 > 0.f ? v3 : 0.f;
                short4 o;
                o.x = (short)f2bf(v0); o.y = (short)f2bf(v1);
                o.z = (short)f2bf(v2); o.w = (short)f2bf(v3);
                *(short4*)(h + rb + colb) = o;
            }
        }
    }
}

// ============ fc2: y[slot][D] = h[slot] @ W2T^T + b2, bf16 out ============
// Block-supply fix: BM2=64 x BN2=128 tiles double the active grid to ~1024
// blocks (4/CU, 16 waves/CU TLP). Wave tile 32x64 (acc[2][4]), LDS 24KB.
// Same 1-phase loop, zero-conflict swizzle, XCD affinity. No tok gather needed.
__global__ void __launch_bounds__(256, 4) fc2_kernel(
    const short* __restrict__ h, const short* __restrict__ W2T, const float* __restrict__ b2,
    short* __restrict__ ybuf, const int* __restrict__ counts, const int* __restrict__ offs) {
    int bid = blockIdx.x;
    int e = bid & 7;
    int r2 = bid >> 3;                  // 0..511
    int m0 = (r2 & 63) * BM2;
    int n0 = (r2 >> 6) * BN2;
    int cnt = counts[e];
    if (m0 >= cnt) return;
    int baseh = offs[e];

    __shared__ short As[BM2 * BK];  // 8 KB
    __shared__ short Bs[BN2 * BK];  // 16 KB

    int t = threadIdx.x;
    int wave = t >> 6, lane = t & 63;

    // A staging: 512 granules -> 2 loads/thread; B: 1024 granules -> 4 loads/thread
    const short* asrc[2]; int dstoA[2];
    const short* bsrc[4]; int dstoB[4];
#pragma unroll
    for (int i = 0; i < 2; i++) {
        int G = i * 256 + t;
        int r = G >> 3, q = G & 7;
        int cks = ((q ^ (r & 7)) << 3);
        asrc[i] = h + (size_t)(baseh + m0 + r) * HDIM + cks;   // overreads stay inside ws
        dstoA[i] = G * 8;
    }
#pragma unroll
    for (int i = 0; i < 4; i++) {
        int G = i * 256 + t;
        int r = G >> 3, q = G & 7;
        int cks = ((q ^ (r & 7)) << 3);
        bsrc[i] = W2T + ((size_t)e * DDIM + n0 + r) * HDIM + cks;
        dstoB[i] = G * 8;
    }

    // 4 waves: 2x2 grid of 32x64 tiles
    int wr = (wave >> 1) * 32, wc = (wave & 1) * 64;
    f32x4 acc[2][4];
    f32x4 zero = {0.f, 0.f, 0.f, 0.f};
#pragma unroll
    for (int m = 0; m < 2; m++)
#pragma unroll
        for (int n = 0; n < 4; n++) acc[m][n] = zero;

    int l15 = lane & 15, l7 = lane & 7, lhi = lane >> 4;
    int aoff[2][2], boff[4][2];
#pragma unroll
    for (int ks = 0; ks < 2; ks++) {
        int q = (lhi + ks * 4) ^ l7;
#pragma unroll
        for (int m = 0; m < 2; m++) aoff[m][ks] = (wr + m * 16 + l15) * BK + (q << 3);
#pragma unroll
        for (int n = 0; n < 4; n++) boff[n][ks] = (wc + n * 16 + l15) * BK + (q << 3);
    }

    const int NT = HDIM / BK;
    for (int kt = 0; kt < NT; ++kt) {
        int k0 = kt * BK;
#pragma unroll
        for (int i = 0; i < 2; i++)
            __builtin_amdgcn_global_load_lds(AS1(asrc[i] + k0), AS3(&As[dstoA[i]]), 16, 0, 0);
#pragma unroll
        for (int i = 0; i < 4; i++)
            __builtin_amdgcn_global_load_lds(AS1(bsrc[i] + k0), AS3(&Bs[dstoB[i]]), 16, 0, 0);
        __syncthreads();
#pragma unroll
        for (int ks = 0; ks < 2; ks++) {
            bf16x8 af[2], bg[4];
#pragma unroll
            for (int m = 0; m < 2; m++) af[m] = *(const bf16x8*)(&As[aoff[m][ks]]);
#pragma unroll
            for (int n = 0; n < 4; n++) bg[n] = *(const bf16x8*)(&Bs[boff[n][ks]]);
            __builtin_amdgcn_s_setprio(1);
#pragma unroll
            for (int m = 0; m < 2; m++)
#pragma unroll
                for (int n = 0; n < 4; n++)
                    acc[m][n] = __builtin_amdgcn_mfma_f32_16x16x32_bf16(bg[n], af[m], acc[m][n], 0, 0, 0);
            __builtin_amdgcn_s_setprio(0);
        }
        __syncthreads();
    }

#pragma unroll
    for (int m = 0; m < 2; m++) {
        int row = m0 + wr + m * 16 + l15;
        if (row < cnt) {
            size_t rb = (size_t)(baseh + row) * DDIM;
#pragma unroll
            for (int n = 0; n < 4; n++) {
                int colb = n0 + wc + n * 16 + (lhi << 2);
                float4 bias = *(const float4*)(b2 + e * DDIM + colb);
                short4 o;
                o.x = (short)f2bf(acc[m][n][0] + bias.x);
                o.y = (short)f2bf(acc[m][n][1] + bias.y);
                o.z = (short)f2bf(acc[m][n][2] + bias.z);
                o.w = (short)f2bf(acc[m][n][3] + bias.w);
                *(short4*)(ybuf + rb + colb) = o;
            }
        }
    }
}

// ---------------- combine: out[b] = g0*y[slot0] + g1*y[slot1] ----------------
__global__ void __launch_bounds__(256) combine_kernel(
    const short* __restrict__ ybuf, const float* __restrict__ gate,
    const int* __restrict__ pair, const int* __restrict__ offs, float* __restrict__ out) {
    int b = blockIdx.x;
    int p0 = pair[b * 2], p1 = pair[b * 2 + 1];
    float g0 = gate[p0], g1 = gate[p1];
    int r0 = offs[p0 >> 12] + (p0 & 4095);
    int r1 = offs[p1 >> 12] + (p1 & 4095);
    const short4* y0 = (const short4*)(ybuf + (size_t)r0 * DDIM);
    const short4* y1 = (const short4*)(ybuf + (size_t)r1 * DDIM);
    float4* o = (float4*)(out + (size_t)b * DDIM);
    int t = threadIdx.x;           // 256 threads * 4 elems = 1024 = DDIM
    short4 a = y0[t], c = y1[t];
    float4 v;
    v.x = g0 * bf2f((unsigned short)a.x) + g1 * bf2f((unsigned short)c.x);
    v.y = g0 * bf2f((unsigned short)a.y) + g1 * bf2f((unsigned short)c.y);
    v.z = g0 * bf2f((unsigned short)a.z) + g1 * bf2f((unsigned short)c.z);
    v.w = g0 * bf2f((unsigned short)a.w) + g1 * bf2f((unsigned short)c.w);
    o[t] = v;
}

extern "C" void kernel_launch(void* const* d_in, const int* in_sizes, int n_in,
                              void* d_out, int out_size, void* d_ws, size_t ws_size,
                              hipStream_t stream) {
    const float* x  = (const float*)d_in[0];
    const float* wg = (const float*)d_in[1];
    const float* W1 = (const float*)d_in[2];
    const float* b1 = (const float*)d_in[3];
    const float* W2 = (const float*)d_in[4];
    const float* b2 = (const float*)d_in[5];
    float* out = (float*)d_out;
    char* ws = (char*)d_ws;

    short* W1T = (short*)(ws + OFF_W1T);
    short* W2T = (short*)(ws + OFF_W2T);
    short* Xb  = (short*)(ws + OFF_XB);
    short* h   = (short*)(ws + OFF_H);
    short* ybuf = (short*)(ws + OFF_Y);
    int* tok   = (int*)(ws + OFF_TOK);
    float* gate = (float*)(ws + OFF_GATE);
    int* pair  = (int*)(ws + OFF_PAIR);
    int* counts = (int*)(ws + OFF_CNT);
    int* offs  = (int*)(ws + OFF_OFFS);
    int* eidx  = (int*)(ws + OFF_EIDX);
    float* gco = (float*)(ws + OFF_GCO);

    hipMemsetAsync(counts, 0, 64, stream);
    gating_logits_kernel<<<B_TOK / 4, 256, 0, stream>>>(x, wg, eidx, gco, Xb);
    build_kernel<<<B_TOK / 256, 256, 0, stream>>>(eidx, gco, counts, tok, gate, pair);
    scan_kernel<<<1, 64, 0, stream>>>(counts, offs);
    tcvt_kernel<<<dim3(HDIM / 64, DDIM / 64, NEXP), 256, 0, stream>>>(W1, W1T, DDIM, HDIM);
    tcvt_kernel<<<dim3(DDIM / 64, HDIM / 64, NEXP), 256, 0, stream>>>(W2, W2T, HDIM, DDIM);
    fc1_kernel<<<NEXP * 32 * (HDIM / BN), 256, 0, stream>>>(Xb, W1T, b1, h, tok, counts, offs);
    fc2_kernel<<<NEXP * (MAXTOK / BM2) * (DDIM / BN2), 256, 0, stream>>>(h, W2T, b2, ybuf, counts, offs);
    combine_kernel<<<B_TOK, 256, 0, stream>>>(ybuf, gate, pair, offs, out);
}

// Round 11
// 174.148 us; speedup vs baseline: 1.1440x; 1.0382x over previous
//
#include <hip/hip_runtime.h>

#define B_TOK 4096
#define DDIM  1024
#define HDIM  2048
#define NEXP  8
#define MAXTOK 4096
#define BK 64
// fc1 tile
#define BM1 64
#define BN1 128
// fc2 tile
#define BM2 64
#define BN2 128

// ws byte offsets (total ~120.3 MB)
#define OFF_W1T  0ull                      // bf16 [E][H][D]  33554432
#define OFF_W2T  33554432ull               // bf16 [E][D][H]  33554432
#define OFF_XB   67108864ull               // bf16 [B][D]      8388608
#define OFF_H    75497472ull               // bf16 [8192][H]  33554432
#define OFF_Y    109051904ull              // bf16 [8192][D]  16777216
#define OFF_TOK  125829120ull              // int  [E][4096]    131072
#define OFF_GATE 125960192ull              // f32  [E][4096]    131072
#define OFF_PAIR 126091264ull              // int  [B][2]        32768
#define OFF_CNT  126124032ull              // int[16]
#define OFF_OFFS 126124096ull              // int[16]
// eidx/gco overlap the ybuf region (dead until fc2; consumed by build_kernel)
#define OFF_EIDX (OFF_Y)                   // int  [B]           16384
#define OFF_GCO  (OFF_Y + 16384ull)        // f32  [B]           16384

typedef __attribute__((ext_vector_type(4))) float f32x4;
typedef __attribute__((ext_vector_type(8))) short bf16x8;

static __device__ __forceinline__ unsigned short f2bf(float f) {
    unsigned u = __builtin_bit_cast(unsigned, f);
    unsigned r = (u + 0x7FFFu + ((u >> 16) & 1u)) >> 16;
    return (unsigned short)r;
}
static __device__ __forceinline__ float bf2f(unsigned short s) {
    unsigned u = ((unsigned)s) << 16;
    return __builtin_bit_cast(float, u);
}

#define AS1(p) ((const __attribute__((address_space(1))) void*)(p))
#define AS3(p) ((__attribute__((address_space(3))) void*)(p))

// ---------------- gating phase A: logits + top-2 + softmax + x->bf16 ----------------
__global__ void __launch_bounds__(256) gating_logits_kernel(
    const float* __restrict__ x, const float* __restrict__ wg,
    int* __restrict__ eidx, float* __restrict__ gco, short* __restrict__ Xb) {
    int wave = threadIdx.x >> 6;
    int lane = threadIdx.x & 63;
    int b = blockIdx.x * 4 + wave;
    float acc[NEXP];
#pragma unroll
    for (int e = 0; e < NEXP; e++) acc[e] = 0.f;
    const float* xr = x + (size_t)b * DDIM;
    short* xbr = Xb + (size_t)b * DDIM;
#pragma unroll
    for (int i = 0; i < DDIM / 64; i++) {
        int d = i * 64 + lane;
        float xv = xr[d];
        xbr[d] = (short)f2bf(xv);
        const float4* wrow = (const float4*)(wg + (size_t)d * NEXP);
        float4 w0 = wrow[0], w1 = wrow[1];
        acc[0] += xv * w0.x; acc[1] += xv * w0.y; acc[2] += xv * w0.z; acc[3] += xv * w0.w;
        acc[4] += xv * w1.x; acc[5] += xv * w1.y; acc[6] += xv * w1.z; acc[7] += xv * w1.w;
    }
#pragma unroll
    for (int off = 32; off >= 1; off >>= 1)
#pragma unroll
        for (int e = 0; e < NEXP; e++) acc[e] += __shfl_xor(acc[e], off);
    if (lane == 0) {
        int i1 = 0; float m1 = acc[0];
        for (int e = 1; e < NEXP; e++) if (acc[e] > m1) { m1 = acc[e]; i1 = e; }
        int i2 = (i1 == 0) ? 1 : 0; float m2 = -1e30f;
        for (int e = 0; e < NEXP; e++) { if (e == i1) continue; if (acc[e] > m2) { m2 = acc[e]; i2 = e; } }
        float g1 = 1.f / (1.f + expf(m2 - m1));
        eidx[b] = i1 | (i2 << 16);
        gco[b] = g1;
    }
}

// ---------------- gating phase B: list build, LDS histogram + 1 global atomic/expert/block ----
__global__ void __launch_bounds__(256) build_kernel(
    const int* __restrict__ eidx, const float* __restrict__ gco,
    int* __restrict__ counts, int* __restrict__ tok,
    float* __restrict__ gate, int* __restrict__ pair) {
    __shared__ int lhist[NEXP];
    __shared__ int gbase[NEXP];
    int t = threadIdx.x;
    if (t < NEXP) lhist[t] = 0;
    __syncthreads();
    int b = blockIdx.x * 256 + t;
    int ep = eidx[b];
    int e1 = ep & 0xffff, e2 = ep >> 16;
    float g1 = gco[b], g2 = 1.f - g1;
    int l1 = atomicAdd(&lhist[e1], 1);
    int l2 = atomicAdd(&lhist[e2], 1);
    __syncthreads();
    if (t < NEXP) gbase[t] = atomicAdd(&counts[t], lhist[t]);
    __syncthreads();
    int s1 = gbase[e1] + l1, s2 = gbase[e2] + l2;
    tok[e1 * MAXTOK + s1] = b; gate[e1 * MAXTOK + s1] = g1; pair[b * 2 + 0] = e1 * MAXTOK + s1;
    tok[e2 * MAXTOK + s2] = b; gate[e2 * MAXTOK + s2] = g2; pair[b * 2 + 1] = e2 * MAXTOK + s2;
}

__global__ void scan_kernel(const int* __restrict__ counts, int* __restrict__ offs) {
    if (threadIdx.x == 0) {
        int s = 0;
        for (int e = 0; e < NEXP; e++) { offs[e] = s; s += counts[e]; }
    }
}

// ---------------- per-expert transpose + f32->bf16: [R][C] -> [C][R] ----------------
__global__ void __launch_bounds__(256) tcvt_kernel(const float* __restrict__ src, short* __restrict__ dst,
                                                   int R, int C) {
    __shared__ float tile[64][65];
    int e = blockIdx.z;
    size_t base = (size_t)e * R * C;
    int r0 = blockIdx.y * 64, c0 = blockIdx.x * 64;
    int t = threadIdx.x;
    int rr = t >> 4, c4 = (t & 15) * 4;
    const float* s = src + base + (size_t)r0 * C + c0;
#pragma unroll
    for (int i = 0; i < 4; i++) {
        float4 v = *(const float4*)(s + (size_t)(rr + i * 16) * C + c4);
        tile[rr + i * 16][c4 + 0] = v.x; tile[rr + i * 16][c4 + 1] = v.y;
        tile[rr + i * 16][c4 + 2] = v.z; tile[rr + i * 16][c4 + 3] = v.w;
    }
    __syncthreads();
    short* d = dst + base + (size_t)c0 * R + r0;
    int hr0 = t >> 4, dc = (t & 15) * 4;
#pragma unroll
    for (int i = 0; i < 4; i++) {
        int hr = hr0 + i * 16;
        short4 o;
        o.x = (short)f2bf(tile[dc + 0][hr]); o.y = (short)f2bf(tile[dc + 1][hr]);
        o.z = (short)f2bf(tile[dc + 2][hr]); o.w = (short)f2bf(tile[dc + 3][hr]);
        *(short4*)(d + (size_t)hr * R + dc) = o;
    }
}

// ============ fc1: h[slot][H] = relu(X[tok] @ W1T^T + b1), bf16 out ============
// Block-supply geometry (validated on fc2 in R10): BM1=64 x BN1=128 tiles,
// wave tile 32x64 (acc[2][4]), 24KB LDS, 4 resident blocks/CU (16 waves/CU).
// 1-phase loop, BK=64 zero-conflict swizzle, gload_lds 16B, XCD affinity.
__global__ void __launch_bounds__(256, 4) fc1_kernel(
    const short* __restrict__ Xb, const short* __restrict__ W1T, const float* __restrict__ b1,
    short* __restrict__ h, const int* __restrict__ tok,
    const int* __restrict__ counts, const int* __restrict__ offs) {
    int bid = blockIdx.x;
    int e = bid & 7;
    int r2 = bid >> 3;                  // 0..1023
    int m0 = (r2 & 63) * BM1;           // m sweeps fastest -> B-panel reuse in L2
    int n0 = (r2 >> 6) * BN1;
    int cnt = counts[e];
    if (m0 >= cnt) return;
    int baseh = offs[e];

    __shared__ short As[BM1 * BK];  // 8 KB
    __shared__ short Bs[BN1 * BK];  // 16 KB

    int t = threadIdx.x;
    int wave = t >> 6, lane = t & 63;

    // A staging: 512 granules -> 2 loads/thread (gathered rows); B: 1024 -> 4 loads/thread
    const short* asrc[2]; int dstoA[2];
    const short* bsrc[4]; int dstoB[4];
#pragma unroll
    for (int i = 0; i < 2; i++) {
        int G = i * 256 + t;
        int r = G >> 3, q = G & 7;
        int cks = ((q ^ (r & 7)) << 3);            // pre-swizzled source chunk (shorts)
        int trow = m0 + r;
        int tid2 = (trow < cnt) ? tok[e * MAXTOK + trow] : 0;
        asrc[i] = Xb + (size_t)tid2 * DDIM + cks;
        dstoA[i] = G * 8;                          // linear LDS dest (shorts)
    }
#pragma unroll
    for (int i = 0; i < 4; i++) {
        int G = i * 256 + t;
        int r = G >> 3, q = G & 7;
        int cks = ((q ^ (r & 7)) << 3);
        bsrc[i] = W1T + ((size_t)e * HDIM + n0 + r) * DDIM + cks;
        dstoB[i] = G * 8;
    }

    // 4 waves: 2x2 grid of 32x64 tiles
    int wr = (wave >> 1) * 32, wc = (wave & 1) * 64;
    f32x4 acc[2][4];
    f32x4 zero = {0.f, 0.f, 0.f, 0.f};
#pragma unroll
    for (int m = 0; m < 2; m++)
#pragma unroll
        for (int n = 0; n < 4; n++) acc[m][n] = zero;

    int l15 = lane & 15, l7 = lane & 7, lhi = lane >> 4;
    int aoff[2][2], boff[4][2];
#pragma unroll
    for (int ks = 0; ks < 2; ks++) {
        int q = (lhi + ks * 4) ^ l7;
#pragma unroll
        for (int m = 0; m < 2; m++) aoff[m][ks] = (wr + m * 16 + l15) * BK + (q << 3);
#pragma unroll
        for (int n = 0; n < 4; n++) boff[n][ks] = (wc + n * 16 + l15) * BK + (q << 3);
    }

    const int NT = DDIM / BK;
    for (int kt = 0; kt < NT; ++kt) {
        int k0 = kt * BK;
#pragma unroll
        for (int i = 0; i < 2; i++)
            __builtin_amdgcn_global_load_lds(AS1(asrc[i] + k0), AS3(&As[dstoA[i]]), 16, 0, 0);
#pragma unroll
        for (int i = 0; i < 4; i++)
            __builtin_amdgcn_global_load_lds(AS1(bsrc[i] + k0), AS3(&Bs[dstoB[i]]), 16, 0, 0);
        __syncthreads();
#pragma unroll
        for (int ks = 0; ks < 2; ks++) {
            bf16x8 af[2], bg[4];
#pragma unroll
            for (int m = 0; m < 2; m++) af[m] = *(const bf16x8*)(&As[aoff[m][ks]]);
#pragma unroll
            for (int n = 0; n < 4; n++) bg[n] = *(const bf16x8*)(&Bs[boff[n][ks]]);
            __builtin_amdgcn_s_setprio(1);
#pragma unroll
            for (int m = 0; m < 2; m++)
#pragma unroll
                for (int n = 0; n < 4; n++)
                    acc[m][n] = __builtin_amdgcn_mfma_f32_16x16x32_bf16(bg[n], af[m], acc[m][n], 0, 0, 0);
            __builtin_amdgcn_s_setprio(0);
        }
        __syncthreads();
    }

    // epilogue: D 4-reg axis = output columns -> short4 stores (+bias, relu)
#pragma unroll
    for (int m = 0; m < 2; m++) {
        int row = m0 + wr + m * 16 + l15;
        if (row < cnt) {
            size_t rb = (size_t)(baseh + row) * HDIM;
#pragma unroll
            for (int n = 0; n < 4; n++) {
                int colb = n0 + wc + n * 16 + (lhi << 2);
                float4 bias = *(const float4*)(b1 + e * HDIM + colb);
                float v0 = acc[m][n][0] + bias.x; v0 = v0 > 0.f ? v0 : 0.f;
                float v1 = acc[m][n][1] + bias.y; v1 = v1 > 0.f ? v1 : 0.f;
                float v2 = acc[m][n][2] + bias.z; v2 = v2 > 0.f ? v2 : 0.f;
                float v3 = acc[m][n][3] + bias.w; v3 = v3 > 0.f ? v3 : 0.f;
                short4 o;
                o.x = (short)f2bf(v0); o.y = (short)f2bf(v1);
                o.z = (short)f2bf(v2); o.w = (short)f2bf(v3);
                *(short4*)(h + rb + colb) = o;
            }
        }
    }
}

// ============ fc2: y[slot][D] = h[slot] @ W2T^T + b2, bf16 out ============
// R10 proven: BM2=64 x BN2=128, 4 blocks/CU, 1-phase, zero-conflict swizzle.
__global__ void __launch_bounds__(256, 4) fc2_kernel(
    const short* __restrict__ h, const short* __restrict__ W2T, const float* __restrict__ b2,
    short* __restrict__ ybuf, const int* __restrict__ counts, const int* __restrict__ offs) {
    int bid = blockIdx.x;
    int e = bid & 7;
    int r2 = bid >> 3;                  // 0..511
    int m0 = (r2 & 63) * BM2;
    int n0 = (r2 >> 6) * BN2;
    int cnt = counts[e];
    if (m0 >= cnt) return;
    int baseh = offs[e];

    __shared__ short As[BM2 * BK];  // 8 KB
    __shared__ short Bs[BN2 * BK];  // 16 KB

    int t = threadIdx.x;
    int wave = t >> 6, lane = t & 63;

    const short* asrc[2]; int dstoA[2];
    const short* bsrc[4]; int dstoB[4];
#pragma unroll
    for (int i = 0; i < 2; i++) {
        int G = i * 256 + t;
        int r = G >> 3, q = G & 7;
        int cks = ((q ^ (r & 7)) << 3);
        asrc[i] = h + (size_t)(baseh + m0 + r) * HDIM + cks;   // overreads stay inside ws
        dstoA[i] = G * 8;
    }
#pragma unroll
    for (int i = 0; i < 4; i++) {
        int G = i * 256 + t;
        int r = G >> 3, q = G & 7;
        int cks = ((q ^ (r & 7)) << 3);
        bsrc[i] = W2T + ((size_t)e * DDIM + n0 + r) * HDIM + cks;
        dstoB[i] = G * 8;
    }

    int wr = (wave >> 1) * 32, wc = (wave & 1) * 64;
    f32x4 acc[2][4];
    f32x4 zero = {0.f, 0.f, 0.f, 0.f};
#pragma unroll
    for (int m = 0; m < 2; m++)
#pragma unroll
        for (int n = 0; n < 4; n++) acc[m][n] = zero;

    int l15 = lane & 15, l7 = lane & 7, lhi = lane >> 4;
    int aoff[2][2], boff[4][2];
#pragma unroll
    for (int ks = 0; ks < 2; ks++) {
        int q = (lhi + ks * 4) ^ l7;
#pragma unroll
        for (int m = 0; m < 2; m++) aoff[m][ks] = (wr + m * 16 + l15) * BK + (q << 3);
#pragma unroll
        for (int n = 0; n < 4; n++) boff[n][ks] = (wc + n * 16 + l15) * BK + (q << 3);
    }

    const int NT = HDIM / BK;
    for (int kt = 0; kt < NT; ++kt) {
        int k0 = kt * BK;
#pragma unroll
        for (int i = 0; i < 2; i++)
            __builtin_amdgcn_global_load_lds(AS1(asrc[i] + k0), AS3(&As[dstoA[i]]), 16, 0, 0);
#pragma unroll
        for (int i = 0; i < 4; i++)
            __builtin_amdgcn_global_load_lds(AS1(bsrc[i] + k0), AS3(&Bs[dstoB[i]]), 16, 0, 0);
        __syncthreads();
#pragma unroll
        for (int ks = 0; ks < 2; ks++) {
            bf16x8 af[2], bg[4];
#pragma unroll
            for (int m = 0; m < 2; m++) af[m] = *(const bf16x8*)(&As[aoff[m][ks]]);
#pragma unroll
            for (int n = 0; n < 4; n++) bg[n] = *(const bf16x8*)(&Bs[boff[n][ks]]);
            __builtin_amdgcn_s_setprio(1);
#pragma unroll
            for (int m = 0; m < 2; m++)
#pragma unroll
                for (int n = 0; n < 4; n++)
                    acc[m][n] = __builtin_amdgcn_mfma_f32_16x16x32_bf16(bg[n], af[m], acc[m][n], 0, 0, 0);
            __builtin_amdgcn_s_setprio(0);
        }
        __syncthreads();
    }

#pragma unroll
    for (int m = 0; m < 2; m++) {
        int row = m0 + wr + m * 16 + l15;
        if (row < cnt) {
            size_t rb = (size_t)(baseh + row) * DDIM;
#pragma unroll
            for (int n = 0; n < 4; n++) {
                int colb = n0 + wc + n * 16 + (lhi << 2);
                float4 bias = *(const float4*)(b2 + e * DDIM + colb);
                short4 o;
                o.x = (short)f2bf(acc[m][n][0] + bias.x);
                o.y = (short)f2bf(acc[m][n][1] + bias.y);
                o.z = (short)f2bf(acc[m][n][2] + bias.z);
                o.w = (short)f2bf(acc[m][n][3] + bias.w);
                *(short4*)(ybuf + rb + colb) = o;
            }
        }
    }
}

// ---------------- combine: out[b] = g0*y[slot0] + g1*y[slot1] ----------------
__global__ void __launch_bounds__(256) combine_kernel(
    const short* __restrict__ ybuf, const float* __restrict__ gate,
    const int* __restrict__ pair, const int* __restrict__ offs, float* __restrict__ out) {
    int b = blockIdx.x;
    int p0 = pair[b * 2], p1 = pair[b * 2 + 1];
    float g0 = gate[p0], g1 = gate[p1];
    int r0 = offs[p0 >> 12] + (p0 & 4095);
    int r1 = offs[p1 >> 12] + (p1 & 4095);
    const short4* y0 = (const short4*)(ybuf + (size_t)r0 * DDIM);
    const short4* y1 = (const short4*)(ybuf + (size_t)r1 * DDIM);
    float4* o = (float4*)(out + (size_t)b * DDIM);
    int t = threadIdx.x;           // 256 threads * 4 elems = 1024 = DDIM
    short4 a = y0[t], c = y1[t];
    float4 v;
    v.x = g0 * bf2f((unsigned short)a.x) + g1 * bf2f((unsigned short)c.x);
    v.y = g0 * bf2f((unsigned short)a.y) + g1 * bf2f((unsigned short)c.y);
    v.z = g0 * bf2f((unsigned short)a.z) + g1 * bf2f((unsigned short)c.z);
    v.w = g0 * bf2f((unsigned short)a.w) + g1 * bf2f((unsigned short)c.w);
    o[t] = v;
}

extern "C" void kernel_launch(void* const* d_in, const int* in_sizes, int n_in,
                              void* d_out, int out_size, void* d_ws, size_t ws_size,
                              hipStream_t stream) {
    const float* x  = (const float*)d_in[0];
    const float* wg = (const float*)d_in[1];
    const float* W1 = (const float*)d_in[2];
    const float* b1 = (const float*)d_in[3];
    const float* W2 = (const float*)d_in[4];
    const float* b2 = (const float*)d_in[5];
    float* out = (float*)d_out;
    char* ws = (char*)d_ws;

    short* W1T = (short*)(ws + OFF_W1T);
    short* W2T = (short*)(ws + OFF_W2T);
    short* Xb  = (short*)(ws + OFF_XB);
    short* h   = (short*)(ws + OFF_H);
    short* ybuf = (short*)(ws + OFF_Y);
    int* tok   = (int*)(ws + OFF_TOK);
    float* gate = (float*)(ws + OFF_GATE);
    int* pair  = (int*)(ws + OFF_PAIR);
    int* counts = (int*)(ws + OFF_CNT);
    int* offs  = (int*)(ws + OFF_OFFS);
    int* eidx  = (int*)(ws + OFF_EIDX);
    float* gco = (float*)(ws + OFF_GCO);

    hipMemsetAsync(counts, 0, 64, stream);
    gating_logits_kernel<<<B_TOK / 4, 256, 0, stream>>>(x, wg, eidx, gco, Xb);
    build_kernel<<<B_TOK / 256, 256, 0, stream>>>(eidx, gco, counts, tok, gate, pair);
    scan_kernel<<<1, 64, 0, stream>>>(counts, offs);
    tcvt_kernel<<<dim3(HDIM / 64, DDIM / 64, NEXP), 256, 0, stream>>>(W1, W1T, DDIM, HDIM);
    tcvt_kernel<<<dim3(DDIM / 64, HDIM / 64, NEXP), 256, 0, stream>>>(W2, W2T, HDIM, DDIM);
    fc1_kernel<<<NEXP * (MAXTOK / BM1) * (HDIM / BN1), 256, 0, stream>>>(Xb, W1T, b1, h, tok, counts, offs);
    fc2_kernel<<<NEXP * (MAXTOK / BM2) * (DDIM / BN2), 256, 0, stream>>>(h, W2T, b2, ybuf, counts, offs);
    combine_kernel<<<B_TOK, 256, 0, stream>>>(ybuf, gate, pair, offs, out);
}